// Round 8
// baseline (622.769 us; speedup 1.0000x reference)
//
#include <hip/hip_runtime.h>
#include <hip/hip_bf16.h>
#include <cstdint>
#include <cstddef>

typedef __attribute__((ext_vector_type(8))) short bf16x8;
typedef __attribute__((ext_vector_type(4))) float f32x4;

__device__ inline float b2f(uint32_t hw) {
  union { uint32_t u; float f; } v; v.u = hw << 16; return v.f;
}
__device__ inline float wlo(uint32_t w) { return b2f(w & 0xffffu); }
__device__ inline float whi(uint32_t w) { return b2f(w >> 16); }
__device__ inline uint32_t packbf(float a, float b) {
  __hip_bfloat162 h{__float2bfloat16(a), __float2bfloat16(b)};
  return *reinterpret_cast<uint32_t*>(&h);
}
// split (r0,r1) into bf16 hi-pair word and bf16 lo-pair word
__device__ inline void splitbf(float r0, float r1, uint32_t& wh, uint32_t& wl) {
  __hip_bfloat16 h0 = __float2bfloat16(r0), h1 = __float2bfloat16(r1);
  float f0 = __bfloat162float(h0), f1 = __bfloat162float(h1);
  __hip_bfloat162 hp{h0, h1};
  wh = *reinterpret_cast<uint32_t*>(&hp);
  wl = packbf(r0 - f0, r1 - f1);
}
__device__ inline float gelu(float v) {
  return 0.5f * v * (1.f + erff(v * 0.70710678118654752f));
}

// ---------- prep: x fp32 NCHW -> bf16 hi/lo swizzled NHWC (word key (p&7)<<2) ----------
__global__ __launch_bounds__(256)
void k_prep_x(const float* __restrict__ x, uint32_t* __restrict__ xh,
              uint32_t* __restrict__ xl) {
  __shared__ float t[64][65];
  int tid = threadIdx.x;
  int p0 = blockIdx.x * 64;
  int b = p0 >> 14, pl0 = p0 & 16383;
  for (int i = tid; i < 64 * 64; i += 256) {
    int c = i >> 6, p = i & 63;
    t[c][p] = x[((size_t)(b * 64 + c) << 14) + pl0 + p];
  }
  __syncthreads();
  for (int s0 = tid; s0 < 64 * 32; s0 += 256) {
    int p = s0 >> 5, wd = s0 & 31;
    int c = 2 * wd;
    uint32_t wh, wl;
    splitbf(t[c][p], t[c + 1][p], wh, wl);
    size_t idx = (size_t)(p0 + p) * 32 + (wd ^ ((p & 7) << 2));
    xh[idx] = wh; xl[idx] = wl;
  }
}

// ---------- prep: deform weight (O,C,3,3) -> (9,O,C/2) pairs, swizzled; hi then lo plane ----------
template <int O, int C>
__global__ void k_prep_wB(const float* __restrict__ wsrc, uint32_t* __restrict__ dst) {
  constexpr int CW = C / 2;
  constexpr int TOT = 9 * O * CW;
  for (int i = blockIdx.x * 256 + threadIdx.x; i < TOT; i += gridDim.x * 256) {
    int k = i / (O * CW);
    int r = i - k * (O * CW);
    int o = r / CW, cp = r - o * CW;
    int c0 = (2 * cp) ^ ((o & 7) << 3);
    float a = wsrc[((size_t)o * C + c0) * 9 + k];
    float bv = wsrc[((size_t)o * C + c0 + 1) * 9 + k];
    uint32_t wh, wl;
    splitbf(a, bv, wh, wl);
    dst[i] = wh; dst[TOT + i] = wl;
  }
}

// ---------- prep: conv weights (18+9 -> 32 padded) -> (9,32,C/2) swizzled; hi then lo ----------
template <int C>
__global__ void k_prep_wC(const float* __restrict__ ow, const float* __restrict__ mw,
                          uint32_t* __restrict__ dst) {
  constexpr int CW = C / 2;
  constexpr int TOT = 9 * 32 * CW;
  for (int i = blockIdx.x * 256 + threadIdx.x; i < TOT; i += gridDim.x * 256) {
    int k = i / (32 * CW);
    int r = i - k * (32 * CW);
    int o = r / CW, cp = r - o * CW;
    int c0 = (2 * cp) ^ ((o & 7) << 3);
    float a = 0.f, bv = 0.f;
    if (o < 18) {
      a  = ow[((size_t)o * C + c0) * 9 + k];
      bv = ow[((size_t)o * C + c0 + 1) * 9 + k];
    } else if (o < 27) {
      a  = mw[((size_t)(o - 18) * C + c0) * 9 + k];
      bv = mw[((size_t)(o - 18) * C + c0 + 1) * 9 + k];
    }
    uint32_t wh, wl;
    splitbf(a, bv, wh, wl);
    dst[i] = wh; dst[TOT + i] = wl;
  }
}

// ---------- MFMA 3x3 conv, hi/lo 3-pass: offsets(18) + mask-logits(9) ----------
template <int C>
__global__ __launch_bounds__(256)
void k_conv(const uint32_t* __restrict__ srch, const uint32_t* __restrict__ srcl,
            const uint32_t* __restrict__ wC,
            const float* __restrict__ ob, const float* __restrict__ mb,
            float* __restrict__ off, float* __restrict__ msk) {
  constexpr int CW = C / 2;
  constexpr int TOTC = 9 * 32 * CW;
  __shared__ uint32_t Ah[64 * CW];
  __shared__ uint32_t Al[64 * CW];
  __shared__ uint32_t Bs[32 * CW];
  __shared__ float Cst[64 * 33];
  int tid = threadIdx.x;
  int lane = tid & 63, w = tid >> 6;
  int p0 = blockIdx.x * 64;
  int b = p0 >> 14;
  int pl0 = p0 & 16383;
  int y = pl0 >> 7, x0 = pl0 & 127;
  int row = w * 16 + (lane & 15);

  f32x4 acc[2] = {{0.f, 0.f, 0.f, 0.f}, {0.f, 0.f, 0.f, 0.f}};

  for (int tap = 0; tap < 9; ++tap) {
    int dy = tap / 3 - 1, dx = tap - 3 * (tap / 3) - 1;
    int yy = y + dy;
    if ((unsigned)yy >= 128u) continue;  // uniform over block
    __syncthreads();
    // stage B hi plane
    for (int i = tid; i < 32 * CW; i += 256) Bs[i] = wC[(size_t)tap * 32 * CW + i];
    // build A (copy both planes from swizzled global)
    int q0 = (b << 14) + yy * 128 + x0 + dx;
    for (int s0 = tid; s0 < 64 * CW; s0 += 256) {
      int i = s0 / CW, cp = s0 - (s0 / CW) * CW;
      int xx = x0 + dx + i;
      bool valid = (unsigned)xx < 128u;
      uint32_t vh = 0u, vl = 0u;
      if (valid) {
        int q = q0 + i;
        int gw = cp ^ ((q & 7) << 2);
        vh = srch[(size_t)q * CW + gw];
        vl = srcl[(size_t)q * CW + gw];
      }
      int slot = cp ^ ((i & 7) << 2);
      Ah[(size_t)i * CW + slot] = vh;
      Al[(size_t)i * CW + slot] = vl;
    }
    __syncthreads();
#pragma unroll
    for (int kk = 0; kk < C / 32; ++kk) {
      int ce = kk * 32 + ((lane >> 4) << 3);
      int boff = (ce ^ ((row & 7) << 3)) * 2;
      bf16x8 ah = *(const bf16x8*)((const char*)Ah + row * (C * 2) + boff);
      bf16x8 al = *(const bf16x8*)((const char*)Al + row * (C * 2) + boff);
#pragma unroll
      for (int nr = 0; nr < 2; ++nr) {
        int col = nr * 16 + (lane & 15);
        bf16x8 bf = *(const bf16x8*)((const char*)Bs + col * (C * 2) +
                                     ((ce ^ ((col & 7) << 3)) * 2));
        acc[nr] = __builtin_amdgcn_mfma_f32_16x16x32_bf16(ah, bf, acc[nr], 0, 0, 0);
        acc[nr] = __builtin_amdgcn_mfma_f32_16x16x32_bf16(al, bf, acc[nr], 0, 0, 0);
      }
    }
    __syncthreads();
    // stage B lo plane, third pass
    for (int i = tid; i < 32 * CW; i += 256) Bs[i] = wC[TOTC + (size_t)tap * 32 * CW + i];
    __syncthreads();
#pragma unroll
    for (int kk = 0; kk < C / 32; ++kk) {
      int ce = kk * 32 + ((lane >> 4) << 3);
      bf16x8 ah = *(const bf16x8*)((const char*)Ah + row * (C * 2) +
                                   ((ce ^ ((row & 7) << 3)) * 2));
#pragma unroll
      for (int nr = 0; nr < 2; ++nr) {
        int col = nr * 16 + (lane & 15);
        bf16x8 bf = *(const bf16x8*)((const char*)Bs + col * (C * 2) +
                                     ((ce ^ ((col & 7) << 3)) * 2));
        acc[nr] = __builtin_amdgcn_mfma_f32_16x16x32_bf16(ah, bf, acc[nr], 0, 0, 0);
      }
    }
  }
  __syncthreads();
#pragma unroll
  for (int nr = 0; nr < 2; ++nr) {
    int col = nr * 16 + (lane & 15);
    float bias = (col < 18) ? ob[col] : ((col < 27) ? mb[col - 18] : 0.f);
#pragma unroll
    for (int r = 0; r < 4; ++r) {
      int p = w * 16 + ((lane >> 4) << 2) + r;
      Cst[p * 33 + col] = acc[nr][r] + bias;
    }
  }
  __syncthreads();
  for (int i = tid; i < 64 * 18; i += 256) {
    int p = i / 18, o = i - 18 * p;
    off[(size_t)p0 * 18 + i] = Cst[p * 33 + o];
  }
  for (int i = tid; i < 64 * 9; i += 256) {
    int p = i / 9, o = i - 9 * p;
    float z = Cst[p * 33 + 18 + o];
    msk[(size_t)p0 * 9 + i] = 2.f / (1.f + expf(-z));
  }
}

// ---------- MFMA deformable conv hi/lo 3-pass + fused channel-LN + GELU ----------
template <int C, int O, bool FINAL>
__global__ __launch_bounds__(256)
void k_deform(const uint32_t* __restrict__ srch, const uint32_t* __restrict__ srcl,
              const float* __restrict__ off, const float* __restrict__ msk,
              const uint32_t* __restrict__ wB,
              const float* __restrict__ lnw, const float* __restrict__ lnb,
              void* __restrict__ outh, void* __restrict__ outl) {
  constexpr int NWN = (O > 64) ? 4 : 2;
  constexpr int NWM = 4 / NWN;
  constexpr int WM = 64 / NWM;
  constexpr int WN = O / NWN;
  constexpr int MR = WM / 16, NR = WN / 16;
  constexpr int CW = C / 2;
  constexpr int TOTB = 9 * O * CW;

  __shared__ uint32_t Ah[64 * CW];
  __shared__ uint32_t Al[64 * CW];
  __shared__ uint32_t Bs[O * CW];
  __shared__ float4 pw[576];
  __shared__ uint2 pq[576];
  __shared__ float Cst[64 * O];
  __shared__ float smean[64], sinv[64];

  int tid = threadIdx.x;
  int lane = tid & 63, w = tid >> 6;
  int wm = w / NWN, wn = w - NWN * (w / NWN);
  int p0 = blockIdx.x * 64;
  int b = p0 >> 14;

  // phase A: bilinear weights (x mask) + clamped corner pixel indices per (p,tap)
  for (int e = tid; e < 576; e += 256) {
    int p = e / 9, k = e - 9 * (e / 9);
    int pix = p0 + p;
    int pl = pix & 16383;
    int yc = pl >> 7, xc = pl & 127;
    float dy = off[(size_t)pix * 18 + 2 * k];
    float dx = off[(size_t)pix * 18 + 2 * k + 1];
    float m = msk[(size_t)pix * 9 + k];
    float py = dy + (float)(k / 3) + (float)(yc - 1);
    float px = dx + (float)(k - 3 * (k / 3)) + (float)(xc - 1);
    float y0f = floorf(py), x0f = floorf(px);
    float ly = py - y0f, lx = px - x0f;
    int y0i = (int)y0f, x0i = (int)x0f;
    int y1i = y0i + 1, x1i = x0i + 1;
    float w00 = (1.f - ly) * (1.f - lx), w01 = (1.f - ly) * lx;
    float w10 = ly * (1.f - lx), w11 = ly * lx;
    if (!(y0i >= 0 && y0i < 128)) { w00 = 0.f; w01 = 0.f; }
    if (!(y1i >= 0 && y1i < 128)) { w10 = 0.f; w11 = 0.f; }
    if (!(x0i >= 0 && x0i < 128)) { w00 = 0.f; w10 = 0.f; }
    if (!(x1i >= 0 && x1i < 128)) { w01 = 0.f; w11 = 0.f; }
    int cy0 = min(max(y0i, 0), 127), cy1 = min(max(y1i, 0), 127);
    int cx0 = min(max(x0i, 0), 127), cx1 = min(max(x1i, 0), 127);
    int base = b << 14;
    uint32_t q00 = base + cy0 * 128 + cx0, q01 = base + cy0 * 128 + cx1;
    uint32_t q10 = base + cy1 * 128 + cx0, q11 = base + cy1 * 128 + cx1;
    pw[e] = make_float4(w00 * m, w01 * m, w10 * m, w11 * m);
    pq[e] = make_uint2(q00 | (q01 << 16), q10 | (q11 << 16));
  }

  f32x4 acc[MR][NR];
#pragma unroll
  for (int mr = 0; mr < MR; ++mr)
#pragma unroll
    for (int nr = 0; nr < NR; ++nr) acc[mr][nr] = {0.f, 0.f, 0.f, 0.f};

  for (int tap = 0; tap < 9; ++tap) {
    __syncthreads();
    // stage B hi plane
    for (int i = tid; i < O * CW; i += 256) Bs[i] = wB[(size_t)tap * O * CW + i];
    // build A: bilinear sample (hi+lo reconstruct), split to hi/lo
    for (int s0 = tid; s0 < 64 * CW; s0 += 256) {
      int p = s0 / CW, cp = s0 - (s0 / CW) * CW;
      float4 wt = pw[p * 9 + tap];
      uint2 qq = pq[p * 9 + tap];
      int q00 = qq.x & 0xffff, q01 = qq.x >> 16;
      int q10 = qq.y & 0xffff, q11 = qq.y >> 16;
      int s00 = cp ^ ((q00 & 7) << 2), s01 = cp ^ ((q01 & 7) << 2);
      int s10 = cp ^ ((q10 & 7) << 2), s11 = cp ^ ((q11 & 7) << 2);
      uint32_t h00 = srch[(size_t)q00 * CW + s00], l00 = srcl[(size_t)q00 * CW + s00];
      uint32_t h01 = srch[(size_t)q01 * CW + s01], l01 = srcl[(size_t)q01 * CW + s01];
      uint32_t h10 = srch[(size_t)q10 * CW + s10], l10 = srcl[(size_t)q10 * CW + s10];
      uint32_t h11 = srch[(size_t)q11 * CW + s11], l11 = srcl[(size_t)q11 * CW + s11];
      float r0 = wt.x * (wlo(h00) + wlo(l00)) + wt.y * (wlo(h01) + wlo(l01))
               + wt.z * (wlo(h10) + wlo(l10)) + wt.w * (wlo(h11) + wlo(l11));
      float r1 = wt.x * (whi(h00) + whi(l00)) + wt.y * (whi(h01) + whi(l01))
               + wt.z * (whi(h10) + whi(l10)) + wt.w * (whi(h11) + whi(l11));
      uint32_t oh, ol;
      splitbf(r0, r1, oh, ol);
      int slot = cp ^ ((p & 7) << 2);
      Ah[(size_t)p * CW + slot] = oh;
      Al[(size_t)p * CW + slot] = ol;
    }
    __syncthreads();
    // pass 0+1: (Ah + Al) x Bhi
#pragma unroll
    for (int kk = 0; kk < C / 32; ++kk) {
      int ce = kk * 32 + ((lane >> 4) << 3);
      bf16x8 afh[MR], afl[MR], bfr[NR];
#pragma unroll
      for (int mr = 0; mr < MR; ++mr) {
        int rowA = wm * WM + mr * 16 + (lane & 15);
        int boff = (ce ^ ((rowA & 7) << 3)) * 2;
        afh[mr] = *(const bf16x8*)((const char*)Ah + rowA * (C * 2) + boff);
        afl[mr] = *(const bf16x8*)((const char*)Al + rowA * (C * 2) + boff);
      }
#pragma unroll
      for (int nr = 0; nr < NR; ++nr) {
        int col = wn * WN + nr * 16 + (lane & 15);
        bfr[nr] = *(const bf16x8*)((const char*)Bs + col * (C * 2) +
                                   ((ce ^ ((col & 7) << 3)) * 2));
      }
#pragma unroll
      for (int mr = 0; mr < MR; ++mr)
#pragma unroll
        for (int nr = 0; nr < NR; ++nr) {
          acc[mr][nr] = __builtin_amdgcn_mfma_f32_16x16x32_bf16(afh[mr], bfr[nr], acc[mr][nr], 0, 0, 0);
          acc[mr][nr] = __builtin_amdgcn_mfma_f32_16x16x32_bf16(afl[mr], bfr[nr], acc[mr][nr], 0, 0, 0);
        }
    }
    __syncthreads();
    // stage B lo plane
    for (int i = tid; i < O * CW; i += 256) Bs[i] = wB[TOTB + (size_t)tap * O * CW + i];
    __syncthreads();
    // pass 2: Ah x Blo
#pragma unroll
    for (int kk = 0; kk < C / 32; ++kk) {
      int ce = kk * 32 + ((lane >> 4) << 3);
      bf16x8 afh[MR], bfr[NR];
#pragma unroll
      for (int mr = 0; mr < MR; ++mr) {
        int rowA = wm * WM + mr * 16 + (lane & 15);
        afh[mr] = *(const bf16x8*)((const char*)Ah + rowA * (C * 2) +
                                   ((ce ^ ((rowA & 7) << 3)) * 2));
      }
#pragma unroll
      for (int nr = 0; nr < NR; ++nr) {
        int col = wn * WN + nr * 16 + (lane & 15);
        bfr[nr] = *(const bf16x8*)((const char*)Bs + col * (C * 2) +
                                   ((ce ^ ((col & 7) << 3)) * 2));
      }
#pragma unroll
      for (int mr = 0; mr < MR; ++mr)
#pragma unroll
        for (int nr = 0; nr < NR; ++nr)
          acc[mr][nr] = __builtin_amdgcn_mfma_f32_16x16x32_bf16(afh[mr], bfr[nr], acc[mr][nr], 0, 0, 0);
    }
  }

  // epilogue: regs -> Cst (f32, word-swizzled), stats, LN+GELU, store
  __syncthreads();
#pragma unroll
  for (int mr = 0; mr < MR; ++mr) {
    int prow = wm * WM + mr * 16 + ((lane >> 4) << 2);
#pragma unroll
    for (int nr = 0; nr < NR; ++nr) {
      int col = wn * WN + nr * 16 + (lane & 15);
#pragma unroll
      for (int r = 0; r < 4; ++r) {
        int p = prow + r;
        Cst[p * O + (col ^ ((p & 15) << 2))] = acc[mr][nr][r];
      }
    }
  }
  __syncthreads();
  {
    int p = tid >> 2, sub = tid & 3;
    float s = 0.f, s2 = 0.f;
#pragma unroll
    for (int j = 0; j < O / 16; ++j) {
      int o0 = (sub * (O / 4) + j * 4) ^ ((p & 15) << 2);
      float4 v = *(const float4*)&Cst[p * O + o0];
      s += v.x + v.y + v.z + v.w;
      s2 += v.x * v.x + v.y * v.y + v.z * v.z + v.w * v.w;
    }
    s += __shfl_xor(s, 1); s += __shfl_xor(s, 2);
    s2 += __shfl_xor(s2, 1); s2 += __shfl_xor(s2, 2);
    if (sub == 0) {
      float mean = s * (1.f / O);
      float var = s2 * (1.f / O) - mean * mean;
      smean[p] = mean;
      sinv[p] = rsqrtf(var + 1e-5f);
    }
  }
  __syncthreads();
  if (!FINAL) {
    uint32_t* dh = (uint32_t*)outh;
    uint32_t* dl = (uint32_t*)outl;
    constexpr int OW = O / 2;
    for (int s0 = tid; s0 < 64 * OW; s0 += 256) {
      int p = s0 / OW, op = s0 - (s0 / OW) * OW;
      int o = 2 * op;
      int ow = o ^ ((p & 15) << 2);
      float c0 = Cst[p * O + ow];
      float c1 = Cst[p * O + ow + 1];
      float m = smean[p], iv = sinv[p];
      float g0 = gelu((c0 - m) * iv * lnw[o] + lnb[o]);
      float g1 = gelu((c1 - m) * iv * lnw[o + 1] + lnb[o + 1]);
      uint32_t wh, wl;
      splitbf(g0, g1, wh, wl);
      size_t idx = (size_t)(p0 + p) * OW + (op ^ ((p & 7) << 2));
      dh[idx] = wh; dl[idx] = wl;
    }
  } else {
    float* dst = (float*)outh;
    int pl0 = p0 & 16383;
    for (int s0 = tid; s0 < 64 * O; s0 += 256) {
      int o = s0 >> 6, p = s0 & 63;
      float c = Cst[p * O + (o ^ ((p & 15) << 2))];
      float m = smean[p], iv = sinv[p];
      float g = gelu((c - m) * iv * lnw[o] + lnb[o]);
      dst[((size_t)(b * 64 + o) << 14) + pl0 + p] = g;
    }
  }
}

// ---------------- launch ----------------
extern "C" void kernel_launch(void* const* d_in, const int* in_sizes, int n_in,
                              void* d_out, int out_size, void* d_ws, size_t ws_size,
                              hipStream_t stream) {
  const float* x      = (const float*)d_in[0];
  const float* off1_w = (const float*)d_in[1];
  const float* off1_b = (const float*)d_in[2];
  const float* mod1_w = (const float*)d_in[3];
  const float* mod1_b = (const float*)d_in[4];
  const float* reg1_w = (const float*)d_in[5];
  const float* ln1_w  = (const float*)d_in[6];
  const float* ln1_b  = (const float*)d_in[7];
  const float* off2_w = (const float*)d_in[8];
  const float* off2_b = (const float*)d_in[9];
  const float* mod2_w = (const float*)d_in[10];
  const float* mod2_b = (const float*)d_in[11];
  const float* reg2_w = (const float*)d_in[12];
  const float* ln2_w  = (const float*)d_in[13];
  const float* ln2_b  = (const float*)d_in[14];
  float* out = (float*)d_out;

  uint32_t* p = (uint32_t*)d_ws;
  uint32_t* xh  = p; p += 32768 * 32;
  uint32_t* xl  = p; p += 32768 * 32;
  uint32_t* h1h = p; p += 32768 * 128;
  uint32_t* h1l = p; p += 32768 * 128;
  float* off1 = (float*)p; p += 32768 * 18;
  float* msk1 = (float*)p; p += 32768 * 9;
  float* off2 = (float*)p; p += 32768 * 18;
  float* msk2 = (float*)p; p += 32768 * 9;
  uint32_t* wB1 = p; p += 2 * 9 * 256 * 32;
  uint32_t* wB2 = p; p += 2 * 9 * 64 * 128;
  uint32_t* wC1 = p; p += 2 * 9 * 32 * 32;
  uint32_t* wC2 = p; p += 2 * 9 * 32 * 128;

  hipLaunchKernelGGL(k_prep_x, dim3(512), dim3(256), 0, stream, x, xh, xl);
  hipLaunchKernelGGL((k_prep_wB<256, 64>), dim3(288), dim3(256), 0, stream, reg1_w, wB1);
  hipLaunchKernelGGL((k_prep_wB<64, 256>), dim3(288), dim3(256), 0, stream, reg2_w, wB2);
  hipLaunchKernelGGL((k_prep_wC<64>),  dim3(36),  dim3(256), 0, stream, off1_w, mod1_w, wC1);
  hipLaunchKernelGGL((k_prep_wC<256>), dim3(144), dim3(256), 0, stream, off2_w, mod2_w, wC2);

  hipLaunchKernelGGL((k_conv<64>), dim3(512), dim3(256), 0, stream,
                     xh, xl, wC1, off1_b, mod1_b, off1, msk1);
  hipLaunchKernelGGL((k_deform<64, 256, false>), dim3(512), dim3(256), 0, stream,
                     xh, xl, off1, msk1, wB1, ln1_w, ln1_b, (void*)h1h, (void*)h1l);
  hipLaunchKernelGGL((k_conv<256>), dim3(512), dim3(256), 0, stream,
                     h1h, h1l, wC2, off2_b, mod2_b, off2, msk2);
  hipLaunchKernelGGL((k_deform<256, 64, true>), dim3(512), dim3(256), 0, stream,
                     h1h, h1l, off2, msk2, wB2, ln2_w, ln2_b, (void*)out, nullptr);
}

// Round 10
// 584.015 us; speedup vs baseline: 1.0664x; 1.0664x over previous
//
#include <hip/hip_runtime.h>
#include <hip/hip_bf16.h>
#include <cstdint>
#include <cstddef>

typedef __attribute__((ext_vector_type(8))) short bf16x8;
typedef __attribute__((ext_vector_type(4))) float f32x4;

__device__ inline float b2f(uint32_t hw) {
  union { uint32_t u; float f; } v; v.u = hw << 16; return v.f;
}
__device__ inline float wlo(uint32_t w) { return b2f(w & 0xffffu); }
__device__ inline float whi(uint32_t w) { return b2f(w >> 16); }
__device__ inline uint32_t packbf(float a, float b) {
  __hip_bfloat162 h{__float2bfloat16(a), __float2bfloat16(b)};
  return *reinterpret_cast<uint32_t*>(&h);
}
// split (r0,r1) into bf16 hi-pair word and bf16 lo-pair word
__device__ inline void splitbf(float r0, float r1, uint32_t& wh, uint32_t& wl) {
  __hip_bfloat16 h0 = __float2bfloat16(r0), h1 = __float2bfloat16(r1);
  float f0 = __bfloat162float(h0), f1 = __bfloat162float(h1);
  __hip_bfloat162 hp{h0, h1};
  wh = *reinterpret_cast<uint32_t*>(&hp);
  wl = packbf(r0 - f0, r1 - f1);
}
__device__ inline float gelu(float v) {
  return 0.5f * v * (1.f + erff(v * 0.70710678118654752f));
}

// ---------- prep: x fp32 NCHW -> bf16 hi/lo swizzled NHWC (word key (p&7)<<2) ----------
__global__ __launch_bounds__(256)
void k_prep_x(const float* __restrict__ x, uint32_t* __restrict__ xh,
              uint32_t* __restrict__ xl) {
  __shared__ float t[64][65];
  int tid = threadIdx.x;
  int p0 = blockIdx.x * 64;
  int b = p0 >> 14, pl0 = p0 & 16383;
  for (int i = tid; i < 64 * 64; i += 256) {
    int c = i >> 6, p = i & 63;
    t[c][p] = x[((size_t)(b * 64 + c) << 14) + pl0 + p];
  }
  __syncthreads();
  for (int s0 = tid; s0 < 64 * 32; s0 += 256) {
    int p = s0 >> 5, wd = s0 & 31;
    int c = 2 * wd;
    uint32_t wh, wl;
    splitbf(t[c][p], t[c + 1][p], wh, wl);
    size_t idx = (size_t)(p0 + p) * 32 + (wd ^ ((p & 7) << 2));
    xh[idx] = wh; xl[idx] = wl;
  }
}

// ---------- prep: deform weight (O,C,3,3) -> (9,O,C/2) pairs, swizzled; hi then lo plane ----------
template <int O, int C>
__global__ void k_prep_wB(const float* __restrict__ wsrc, uint32_t* __restrict__ dst) {
  constexpr int CW = C / 2;
  constexpr int TOT = 9 * O * CW;
  for (int i = blockIdx.x * 256 + threadIdx.x; i < TOT; i += gridDim.x * 256) {
    int k = i / (O * CW);
    int r = i - k * (O * CW);
    int o = r / CW, cp = r - o * CW;
    int c0 = (2 * cp) ^ ((o & 7) << 3);
    float a = wsrc[((size_t)o * C + c0) * 9 + k];
    float bv = wsrc[((size_t)o * C + c0 + 1) * 9 + k];
    uint32_t wh, wl;
    splitbf(a, bv, wh, wl);
    dst[i] = wh; dst[TOT + i] = wl;
  }
}

// ---------- prep: conv weights (18+9 -> 32 padded) -> (9,32,C/2) swizzled; hi then lo ----------
template <int C>
__global__ void k_prep_wC(const float* __restrict__ ow, const float* __restrict__ mw,
                          uint32_t* __restrict__ dst) {
  constexpr int CW = C / 2;
  constexpr int TOT = 9 * 32 * CW;
  for (int i = blockIdx.x * 256 + threadIdx.x; i < TOT; i += gridDim.x * 256) {
    int k = i / (32 * CW);
    int r = i - k * (32 * CW);
    int o = r / CW, cp = r - o * CW;
    int c0 = (2 * cp) ^ ((o & 7) << 3);
    float a = 0.f, bv = 0.f;
    if (o < 18) {
      a  = ow[((size_t)o * C + c0) * 9 + k];
      bv = ow[((size_t)o * C + c0 + 1) * 9 + k];
    } else if (o < 27) {
      a  = mw[((size_t)(o - 18) * C + c0) * 9 + k];
      bv = mw[((size_t)(o - 18) * C + c0 + 1) * 9 + k];
    }
    uint32_t wh, wl;
    splitbf(a, bv, wh, wl);
    dst[i] = wh; dst[TOT + i] = wl;
  }
}

// ---------- MFMA 3x3 conv, hi/lo 3-pass: offsets(18) + mask-logits(9) ----------
template <int C>
__global__ __launch_bounds__(256)
void k_conv(const uint32_t* __restrict__ srch, const uint32_t* __restrict__ srcl,
            const uint32_t* __restrict__ wC,
            const float* __restrict__ ob, const float* __restrict__ mb,
            float* __restrict__ off, float* __restrict__ msk) {
  constexpr int CW = C / 2;
  constexpr int TOTC = 9 * 32 * CW;
  __shared__ uint32_t Ah[64 * CW];
  __shared__ uint32_t Al[64 * CW];
  __shared__ uint32_t Bs[32 * CW];
  __shared__ float Cst[64 * 33];
  int tid = threadIdx.x;
  int lane = tid & 63, w = tid >> 6;
  int p0 = blockIdx.x * 64;
  int b = p0 >> 14;
  int pl0 = p0 & 16383;
  int y = pl0 >> 7, x0 = pl0 & 127;
  int row = w * 16 + (lane & 15);

  f32x4 acc[2] = {{0.f, 0.f, 0.f, 0.f}, {0.f, 0.f, 0.f, 0.f}};

  for (int tap = 0; tap < 9; ++tap) {
    int dy = tap / 3 - 1, dx = tap - 3 * (tap / 3) - 1;
    int yy = y + dy;
    if ((unsigned)yy >= 128u) continue;  // uniform over block
    __syncthreads();
    // stage B hi plane
    for (int i = tid; i < 32 * CW; i += 256) Bs[i] = wC[(size_t)tap * 32 * CW + i];
    // build A (copy both planes from swizzled global)
    int q0 = (b << 14) + yy * 128 + x0 + dx;
    for (int s0 = tid; s0 < 64 * CW; s0 += 256) {
      int i = s0 / CW, cp = s0 - (s0 / CW) * CW;
      int xx = x0 + dx + i;
      bool valid = (unsigned)xx < 128u;
      uint32_t vh = 0u, vl = 0u;
      if (valid) {
        int q = q0 + i;
        int gw = cp ^ ((q & 7) << 2);
        vh = srch[(size_t)q * CW + gw];
        vl = srcl[(size_t)q * CW + gw];
      }
      int slot = cp ^ ((i & 7) << 2);
      Ah[(size_t)i * CW + slot] = vh;
      Al[(size_t)i * CW + slot] = vl;
    }
    __syncthreads();
#pragma unroll
    for (int kk = 0; kk < C / 32; ++kk) {
      int ce = kk * 32 + ((lane >> 4) << 3);
      int boff = (ce ^ ((row & 7) << 3)) * 2;
      bf16x8 ah = *(const bf16x8*)((const char*)Ah + row * (C * 2) + boff);
      bf16x8 al = *(const bf16x8*)((const char*)Al + row * (C * 2) + boff);
#pragma unroll
      for (int nr = 0; nr < 2; ++nr) {
        int col = nr * 16 + (lane & 15);
        bf16x8 bf = *(const bf16x8*)((const char*)Bs + col * (C * 2) +
                                     ((ce ^ ((col & 7) << 3)) * 2));
        acc[nr] = __builtin_amdgcn_mfma_f32_16x16x32_bf16(ah, bf, acc[nr], 0, 0, 0);
        acc[nr] = __builtin_amdgcn_mfma_f32_16x16x32_bf16(al, bf, acc[nr], 0, 0, 0);
      }
    }
    __syncthreads();
    // stage B lo plane, third pass
    for (int i = tid; i < 32 * CW; i += 256) Bs[i] = wC[TOTC + (size_t)tap * 32 * CW + i];
    __syncthreads();
#pragma unroll
    for (int kk = 0; kk < C / 32; ++kk) {
      int ce = kk * 32 + ((lane >> 4) << 3);
      bf16x8 ah = *(const bf16x8*)((const char*)Ah + row * (C * 2) +
                                   ((ce ^ ((row & 7) << 3)) * 2));
#pragma unroll
      for (int nr = 0; nr < 2; ++nr) {
        int col = nr * 16 + (lane & 15);
        bf16x8 bf = *(const bf16x8*)((const char*)Bs + col * (C * 2) +
                                     ((ce ^ ((col & 7) << 3)) * 2));
        acc[nr] = __builtin_amdgcn_mfma_f32_16x16x32_bf16(ah, bf, acc[nr], 0, 0, 0);
      }
    }
  }
  __syncthreads();
#pragma unroll
  for (int nr = 0; nr < 2; ++nr) {
    int col = nr * 16 + (lane & 15);
    float bias = (col < 18) ? ob[col] : ((col < 27) ? mb[col - 18] : 0.f);
#pragma unroll
    for (int r = 0; r < 4; ++r) {
      int p = w * 16 + ((lane >> 4) << 2) + r;
      Cst[p * 33 + col] = acc[nr][r] + bias;
    }
  }
  __syncthreads();
  for (int i = tid; i < 64 * 18; i += 256) {
    int p = i / 18, o = i - 18 * p;
    off[(size_t)p0 * 18 + i] = Cst[p * 33 + o];
  }
  for (int i = tid; i < 64 * 9; i += 256) {
    int p = i / 9, o = i - 9 * p;
    float z = Cst[p * 33 + 18 + o];
    msk[(size_t)p0 * 9 + i] = 2.f / (1.f + expf(-z));
  }
}

// ---------- MFMA deformable conv hi/lo 3-pass + fused channel-LN + GELU ----------
template <int C, int O, bool FINAL>
__global__ __launch_bounds__(256)
void k_deform(const uint32_t* __restrict__ srch, const uint32_t* __restrict__ srcl,
              const float* __restrict__ off, const float* __restrict__ msk,
              const uint32_t* __restrict__ wB,
              const float* __restrict__ lnw, const float* __restrict__ lnb,
              void* __restrict__ outh, void* __restrict__ outl) {
  constexpr int NWN = (O > 64) ? 4 : 2;
  constexpr int NWM = 4 / NWN;
  constexpr int WM = 64 / NWM;
  constexpr int WN = O / NWN;
  constexpr int MR = WM / 16, NR = WN / 16;
  constexpr int CW = C / 2;
  constexpr int TOTB = 9 * O * CW;

  __shared__ uint32_t Ah[64 * CW];
  __shared__ uint32_t Al[64 * CW];
  __shared__ uint32_t Bs[O * CW];
  __shared__ float4 pw[576];
  __shared__ uint2 pq[576];
  __shared__ float Cst[FINAL ? 64 * 64 : 1];         // only the fused-LN (O=64) path
  __shared__ float sws[FINAL ? 1 : 256];             // [wn][row] partial sums
  __shared__ float sws2[FINAL ? 1 : 256];
  __shared__ float smean[FINAL ? 64 : 1], sinv[FINAL ? 64 : 1];

  int tid = threadIdx.x;
  int lane = tid & 63, w = tid >> 6;
  int wm = w / NWN, wn = w - NWN * (w / NWN);
  int p0 = blockIdx.x * 64;
  int b = p0 >> 14;

  // phase A: bilinear weights (x mask) + clamped corner pixel indices per (p,tap)
  for (int e = tid; e < 576; e += 256) {
    int p = e / 9, k = e - 9 * (e / 9);
    int pix = p0 + p;
    int pl = pix & 16383;
    int yc = pl >> 7, xc = pl & 127;
    float dy = off[(size_t)pix * 18 + 2 * k];
    float dx = off[(size_t)pix * 18 + 2 * k + 1];
    float m = msk[(size_t)pix * 9 + k];
    float py = dy + (float)(k / 3) + (float)(yc - 1);
    float px = dx + (float)(k - 3 * (k / 3)) + (float)(xc - 1);
    float y0f = floorf(py), x0f = floorf(px);
    float ly = py - y0f, lx = px - x0f;
    int y0i = (int)y0f, x0i = (int)x0f;
    int y1i = y0i + 1, x1i = x0i + 1;
    float w00 = (1.f - ly) * (1.f - lx), w01 = (1.f - ly) * lx;
    float w10 = ly * (1.f - lx), w11 = ly * lx;
    if (!(y0i >= 0 && y0i < 128)) { w00 = 0.f; w01 = 0.f; }
    if (!(y1i >= 0 && y1i < 128)) { w10 = 0.f; w11 = 0.f; }
    if (!(x0i >= 0 && x0i < 128)) { w00 = 0.f; w10 = 0.f; }
    if (!(x1i >= 0 && x1i < 128)) { w01 = 0.f; w11 = 0.f; }
    int cy0 = min(max(y0i, 0), 127), cy1 = min(max(y1i, 0), 127);
    int cx0 = min(max(x0i, 0), 127), cx1 = min(max(x1i, 0), 127);
    int base = b << 14;
    uint32_t q00 = base + cy0 * 128 + cx0, q01 = base + cy0 * 128 + cx1;
    uint32_t q10 = base + cy1 * 128 + cx0, q11 = base + cy1 * 128 + cx1;
    pw[e] = make_float4(w00 * m, w01 * m, w10 * m, w11 * m);
    pq[e] = make_uint2(q00 | (q01 << 16), q10 | (q11 << 16));
  }

  f32x4 acc[MR][NR];
#pragma unroll
  for (int mr = 0; mr < MR; ++mr)
#pragma unroll
    for (int nr = 0; nr < NR; ++nr) acc[mr][nr] = {0.f, 0.f, 0.f, 0.f};

  for (int tap = 0; tap < 9; ++tap) {
    __syncthreads();
    // stage B hi plane
    for (int i = tid; i < O * CW; i += 256) Bs[i] = wB[(size_t)tap * O * CW + i];
    // build A: bilinear sample (hi+lo reconstruct), split to hi/lo
    for (int s0 = tid; s0 < 64 * CW; s0 += 256) {
      int p = s0 / CW, cp = s0 - (s0 / CW) * CW;
      float4 wt = pw[p * 9 + tap];
      uint2 qq = pq[p * 9 + tap];
      int q00 = qq.x & 0xffff, q01 = qq.x >> 16;
      int q10 = qq.y & 0xffff, q11 = qq.y >> 16;
      int s00 = cp ^ ((q00 & 7) << 2), s01 = cp ^ ((q01 & 7) << 2);
      int s10 = cp ^ ((q10 & 7) << 2), s11 = cp ^ ((q11 & 7) << 2);
      uint32_t h00 = srch[(size_t)q00 * CW + s00], l00 = srcl[(size_t)q00 * CW + s00];
      uint32_t h01 = srch[(size_t)q01 * CW + s01], l01 = srcl[(size_t)q01 * CW + s01];
      uint32_t h10 = srch[(size_t)q10 * CW + s10], l10 = srcl[(size_t)q10 * CW + s10];
      uint32_t h11 = srch[(size_t)q11 * CW + s11], l11 = srcl[(size_t)q11 * CW + s11];
      float r0 = wt.x * (wlo(h00) + wlo(l00)) + wt.y * (wlo(h01) + wlo(l01))
               + wt.z * (wlo(h10) + wlo(l10)) + wt.w * (wlo(h11) + wlo(l11));
      float r1 = wt.x * (whi(h00) + whi(l00)) + wt.y * (whi(h01) + whi(l01))
               + wt.z * (whi(h10) + whi(l10)) + wt.w * (whi(h11) + whi(l11));
      uint32_t oh, ol;
      splitbf(r0, r1, oh, ol);
      int slot = cp ^ ((p & 7) << 2);
      Ah[(size_t)p * CW + slot] = oh;
      Al[(size_t)p * CW + slot] = ol;
    }
    __syncthreads();
    // pass 0+1: (Ah + Al) x Bhi
#pragma unroll
    for (int kk = 0; kk < C / 32; ++kk) {
      int ce = kk * 32 + ((lane >> 4) << 3);
      bf16x8 afh[MR], afl[MR], bfr[NR];
#pragma unroll
      for (int mr = 0; mr < MR; ++mr) {
        int rowA = wm * WM + mr * 16 + (lane & 15);
        int boff = (ce ^ ((rowA & 7) << 3)) * 2;
        afh[mr] = *(const bf16x8*)((const char*)Ah + rowA * (C * 2) + boff);
        afl[mr] = *(const bf16x8*)((const char*)Al + rowA * (C * 2) + boff);
      }
#pragma unroll
      for (int nr = 0; nr < NR; ++nr) {
        int col = wn * WN + nr * 16 + (lane & 15);
        bfr[nr] = *(const bf16x8*)((const char*)Bs + col * (C * 2) +
                                   ((ce ^ ((col & 7) << 3)) * 2));
      }
#pragma unroll
      for (int mr = 0; mr < MR; ++mr)
#pragma unroll
        for (int nr = 0; nr < NR; ++nr) {
          acc[mr][nr] = __builtin_amdgcn_mfma_f32_16x16x32_bf16(afh[mr], bfr[nr], acc[mr][nr], 0, 0, 0);
          acc[mr][nr] = __builtin_amdgcn_mfma_f32_16x16x32_bf16(afl[mr], bfr[nr], acc[mr][nr], 0, 0, 0);
        }
    }
    __syncthreads();
    // stage B lo plane
    for (int i = tid; i < O * CW; i += 256) Bs[i] = wB[TOTB + (size_t)tap * O * CW + i];
    __syncthreads();
    // pass 2: Ah x Blo
#pragma unroll
    for (int kk = 0; kk < C / 32; ++kk) {
      int ce = kk * 32 + ((lane >> 4) << 3);
      bf16x8 afh[MR], bfr[NR];
#pragma unroll
      for (int mr = 0; mr < MR; ++mr) {
        int rowA = wm * WM + mr * 16 + (lane & 15);
        afh[mr] = *(const bf16x8*)((const char*)Ah + rowA * (C * 2) +
                                   ((ce ^ ((rowA & 7) << 3)) * 2));
      }
#pragma unroll
      for (int nr = 0; nr < NR; ++nr) {
        int col = wn * WN + nr * 16 + (lane & 15);
        bfr[nr] = *(const bf16x8*)((const char*)Bs + col * (C * 2) +
                                   ((ce ^ ((col & 7) << 3)) * 2));
      }
#pragma unroll
      for (int mr = 0; mr < MR; ++mr)
#pragma unroll
        for (int nr = 0; nr < NR; ++nr)
          acc[mr][nr] = __builtin_amdgcn_mfma_f32_16x16x32_bf16(afh[mr], bfr[nr], acc[mr][nr], 0, 0, 0);
    }
  }

  if (!FINAL) {
    // ---- register LN: per-thread partials -> 16-lane butterfly -> sws[wn][row] ----
#pragma unroll
    for (int mr = 0; mr < MR; ++mr) {
#pragma unroll
      for (int r = 0; r < 4; ++r) {
        float s = 0.f, s2 = 0.f;
#pragma unroll
        for (int nr = 0; nr < NR; ++nr) {
          float v = acc[mr][nr][r];
          s += v; s2 += v * v;
        }
        s += __shfl_xor(s, 1); s2 += __shfl_xor(s2, 1);
        s += __shfl_xor(s, 2); s2 += __shfl_xor(s2, 2);
        s += __shfl_xor(s, 4); s2 += __shfl_xor(s2, 4);
        s += __shfl_xor(s, 8); s2 += __shfl_xor(s2, 8);
        if ((lane & 15) == 0) {
          int p = mr * 16 + ((lane >> 4) << 2) + r;
          sws[wn * 64 + p] = s;
          sws2[wn * 64 + p] = s2;
        }
      }
    }
    __syncthreads();
    uint32_t* dh = (uint32_t*)outh;
    uint32_t* dl = (uint32_t*)outl;
#pragma unroll
    for (int mr = 0; mr < MR; ++mr) {
#pragma unroll
      for (int r = 0; r < 4; ++r) {
        int p = mr * 16 + ((lane >> 4) << 2) + r;
        int pix = p0 + p;
        int key = (p & 7) << 2;
        float mean = (sws[p] + sws[64 + p] + sws[128 + p] + sws[192 + p]) * (1.f / O);
        float ex2 = (sws2[p] + sws2[64 + p] + sws2[128 + p] + sws2[192 + p]) * (1.f / O);
        float inv = rsqrtf(ex2 - mean * mean + 1e-5f);
#pragma unroll
        for (int nr = 0; nr < NR; ++nr) {
          int col = wn * WN + nr * 16 + (lane & 15);
          float g = gelu((acc[mr][nr][r] - mean) * inv * lnw[col] + lnb[col]);
          float gp = __shfl_xor(g, 1);
          if (!(lane & 1)) {
            uint32_t wh, wl;
            splitbf(g, gp, wh, wl);
            size_t idx = (size_t)pix * (O / 2) + ((col >> 1) ^ key);
            dh[idx] = wh; dl[idx] = wl;
          }
        }
      }
    }
  } else {
    // ---- R8 epilogue: Cst round-trip, block LN stats, NCHW store ----
    __syncthreads();
#pragma unroll
    for (int mr = 0; mr < MR; ++mr) {
      int prow = wm * WM + mr * 16 + ((lane >> 4) << 2);
#pragma unroll
      for (int nr = 0; nr < NR; ++nr) {
        int col = wn * WN + nr * 16 + (lane & 15);
#pragma unroll
        for (int r = 0; r < 4; ++r) {
          int p = prow + r;
          Cst[p * O + (col ^ ((p & 15) << 2))] = acc[mr][nr][r];
        }
      }
    }
    __syncthreads();
    {
      int p = tid >> 2, sub = tid & 3;
      float s = 0.f, s2 = 0.f;
#pragma unroll
      for (int j = 0; j < O / 16; ++j) {
        int o0 = (sub * (O / 4) + j * 4) ^ ((p & 15) << 2);
        float4 v = *(const float4*)&Cst[p * O + o0];
        s += v.x + v.y + v.z + v.w;
        s2 += v.x * v.x + v.y * v.y + v.z * v.z + v.w * v.w;
      }
      s += __shfl_xor(s, 1); s += __shfl_xor(s, 2);
      s2 += __shfl_xor(s2, 1); s2 += __shfl_xor(s2, 2);
      if (sub == 0) {
        float mean = s * (1.f / O);
        float var = s2 * (1.f / O) - mean * mean;
        smean[p] = mean;
        sinv[p] = rsqrtf(var + 1e-5f);
      }
    }
    __syncthreads();
    float* dst = (float*)outh;
    int pl0 = p0 & 16383;
    for (int s0 = tid; s0 < 64 * O; s0 += 256) {
      int o = s0 >> 6, p = s0 & 63;
      float c = Cst[p * O + (o ^ ((p & 15) << 2))];
      float m = smean[p], iv = sinv[p];
      float g = gelu((c - m) * iv * lnw[o] + lnb[o]);
      dst[((size_t)(b * 64 + o) << 14) + pl0 + p] = g;
    }
  }
}

// ---------------- launch ----------------
extern "C" void kernel_launch(void* const* d_in, const int* in_sizes, int n_in,
                              void* d_out, int out_size, void* d_ws, size_t ws_size,
                              hipStream_t stream) {
  const float* x      = (const float*)d_in[0];
  const float* off1_w = (const float*)d_in[1];
  const float* off1_b = (const float*)d_in[2];
  const float* mod1_w = (const float*)d_in[3];
  const float* mod1_b = (const float*)d_in[4];
  const float* reg1_w = (const float*)d_in[5];
  const float* ln1_w  = (const float*)d_in[6];
  const float* ln1_b  = (const float*)d_in[7];
  const float* off2_w = (const float*)d_in[8];
  const float* off2_b = (const float*)d_in[9];
  const float* mod2_w = (const float*)d_in[10];
  const float* mod2_b = (const float*)d_in[11];
  const float* reg2_w = (const float*)d_in[12];
  const float* ln2_w  = (const float*)d_in[13];
  const float* ln2_b  = (const float*)d_in[14];
  float* out = (float*)d_out;

  uint32_t* p = (uint32_t*)d_ws;
  uint32_t* xh  = p; p += 32768 * 32;
  uint32_t* xl  = p; p += 32768 * 32;
  uint32_t* h1h = p; p += 32768 * 128;
  uint32_t* h1l = p; p += 32768 * 128;
  float* off1 = (float*)p; p += 32768 * 18;
  float* msk1 = (float*)p; p += 32768 * 9;
  float* off2 = (float*)p; p += 32768 * 18;
  float* msk2 = (float*)p; p += 32768 * 9;
  uint32_t* wB1 = p; p += 2 * 9 * 256 * 32;
  uint32_t* wB2 = p; p += 2 * 9 * 64 * 128;
  uint32_t* wC1 = p; p += 2 * 9 * 32 * 32;
  uint32_t* wC2 = p; p += 2 * 9 * 32 * 128;

  hipLaunchKernelGGL(k_prep_x, dim3(512), dim3(256), 0, stream, x, xh, xl);
  hipLaunchKernelGGL((k_prep_wB<256, 64>), dim3(288), dim3(256), 0, stream, reg1_w, wB1);
  hipLaunchKernelGGL((k_prep_wB<64, 256>), dim3(288), dim3(256), 0, stream, reg2_w, wB2);
  hipLaunchKernelGGL((k_prep_wC<64>),  dim3(36),  dim3(256), 0, stream, off1_w, mod1_w, wC1);
  hipLaunchKernelGGL((k_prep_wC<256>), dim3(144), dim3(256), 0, stream, off2_w, mod2_w, wC2);

  hipLaunchKernelGGL((k_conv<64>), dim3(512), dim3(256), 0, stream,
                     xh, xl, wC1, off1_b, mod1_b, off1, msk1);
  hipLaunchKernelGGL((k_deform<64, 256, false>), dim3(512), dim3(256), 0, stream,
                     xh, xl, off1, msk1, wB1, ln1_w, ln1_b, (void*)h1h, (void*)h1l);
  hipLaunchKernelGGL((k_conv<256>), dim3(512), dim3(256), 0, stream,
                     h1h, h1l, wC2, off2_b, mod2_b, off2, msk2);
  hipLaunchKernelGGL((k_deform<256, 64, true>), dim3(512), dim3(256), 0, stream,
                     h1h, h1l, off2, msk2, wB2, ln2_w, ln2_b, (void*)out, nullptr);
}